// Round 1
// baseline (1014.281 us; speedup 1.0000x reference)
//
#include <hip/hip_runtime.h>
#include <math.h>

// Problem constants (fixed by the reference)
#define B_   2
#define S_   2048
#define DIM_ 1024
#define H_   16
#define HD_  64
#define BS_  (B_ * S_)        // 4096 rows
#define SCALE 0.125f          // 1/sqrt(64)

// ---------------------------------------------------------------------------
// GEMM: Y[M=4096][N=1024] = X @ W + bias
// hmIn : X is head-major [B][H][S][64] instead of row-major [r][k]
// hmOut: Y written head-major [B][H][S][64] instead of row-major [r][c]
// Tile 64x64, BK=16, 256 threads, 4x4 register blocking.
// ---------------------------------------------------------------------------
__global__ __launch_bounds__(256) void gemm4096(
    const float* __restrict__ X, const float* __restrict__ W,
    const float* __restrict__ bias, float* __restrict__ Y,
    int hmIn, int hmOut)
{
    __shared__ float As[16][68];   // [BK][BM+4] transposed A tile
    __shared__ float Bs[16][68];   // [BK][BN+4]

    const int tid  = threadIdx.x;
    const int row0 = blockIdx.x * 64;
    const int col0 = blockIdx.y * 64;
    const int tx = tid & 15, ty = tid >> 4;

    float acc[4][4];
#pragma unroll
    for (int i = 0; i < 4; ++i)
#pragma unroll
        for (int j = 0; j < 4; ++j) acc[i][j] = 0.f;

    for (int k0 = 0; k0 < DIM_; k0 += 16) {
        // ---- stage X tile (64 rows x 16 k), transposed into As[k][m]
        {
            const int xr = tid >> 2;            // 0..63
            const int xk = (tid & 3) * 4;       // 0,4,8,12
            const int rr = row0 + xr;
            const int kk = k0 + xk;
            size_t addr;
            if (hmIn)  // X[r][k] = buf[((b*16 + h)*2048 + s)*64 + d]
                addr = (((size_t)(rr >> 11) * H_ + (kk >> 6)) * S_ + (rr & (S_ - 1))) * HD_ + (kk & 63);
            else
                addr = (size_t)rr * DIM_ + kk;
            const float4 xv = *(const float4*)(X + addr);
            As[xk + 0][xr] = xv.x;
            As[xk + 1][xr] = xv.y;
            As[xk + 2][xr] = xv.z;
            As[xk + 3][xr] = xv.w;
        }
        // ---- stage W tile (16 k x 64 cols)
        {
            const int wk = tid >> 4;            // 0..15
            const int wc = (tid & 15) * 4;      // 0..60
            *(float4*)&Bs[wk][wc] = *(const float4*)(W + (size_t)(k0 + wk) * DIM_ + col0 + wc);
        }
        __syncthreads();

#pragma unroll
        for (int kk = 0; kk < 16; ++kk) {
            const float4 a4 = *(const float4*)&As[kk][ty * 4];
            const float4 b4 = *(const float4*)&Bs[kk][tx * 4];
            acc[0][0] += a4.x * b4.x; acc[0][1] += a4.x * b4.y; acc[0][2] += a4.x * b4.z; acc[0][3] += a4.x * b4.w;
            acc[1][0] += a4.y * b4.x; acc[1][1] += a4.y * b4.y; acc[1][2] += a4.y * b4.z; acc[1][3] += a4.y * b4.w;
            acc[2][0] += a4.z * b4.x; acc[2][1] += a4.z * b4.y; acc[2][2] += a4.z * b4.z; acc[2][3] += a4.z * b4.w;
            acc[3][0] += a4.w * b4.x; acc[3][1] += a4.w * b4.y; acc[3][2] += a4.w * b4.z; acc[3][3] += a4.w * b4.w;
        }
        __syncthreads();
    }

    // ---- epilogue: bias + store (float4 along columns)
    const int cc = col0 + tx * 4;
    const float4 bv = *(const float4*)(bias + cc);
#pragma unroll
    for (int i = 0; i < 4; ++i) {
        const int rr = row0 + ty * 4 + i;
        float4 ov;
        ov.x = acc[i][0] + bv.x;
        ov.y = acc[i][1] + bv.y;
        ov.z = acc[i][2] + bv.z;
        ov.w = acc[i][3] + bv.w;
        size_t addr;
        if (hmOut)
            addr = (((size_t)(rr >> 11) * H_ + (cc >> 6)) * S_ + (rr & (S_ - 1))) * HD_ + (cc & 63);
        else
            addr = (size_t)rr * DIM_ + cc;
        *(float4*)(Y + addr) = ov;
    }
}

// ---------------------------------------------------------------------------
// RoPE in-place on a [B*H][S][64] buffer.
// out[j]    = x[2j]*cos - x[2j+1]*sin        (j < 32)
// out[32+j] = x[2j]*sin + x[2j+1]*cos
// One 32-thread group per row; 8 rows per 256-thread block.
// ---------------------------------------------------------------------------
__global__ __launch_bounds__(256) void rope_inplace(float* __restrict__ T,
                                                    const float* __restrict__ theta)
{
    const int row = blockIdx.x * 8 + (threadIdx.x >> 5);  // 0 .. B*H*S-1
    const int j   = threadIdx.x & 31;
    const int s   = row & (S_ - 1);
    float* rp = T + (size_t)row * HD_;
    const float2 p = *(const float2*)(rp + 2 * j);
    const float ang = (float)s * theta[j];
    float sn, cs;
    sincosf(ang, &sn, &cs);
    const float o1 = p.x * cs - p.y * sn;
    const float o2 = p.x * sn + p.y * cs;
    __syncthreads();   // all reads complete before in-place writes
    rp[j]      = o1;
    rp[32 + j] = o2;
}

// ---------------------------------------------------------------------------
// Causal flash attention, fp32.
// Grid: (B*H, S/64). Block 256 threads.
// Thread (r = tid>>2, g = tid&3): owns q-row r, score columns j = g+4*jj,
// output columns d = g*16 .. g*16+15.
// Output written IN PLACE into the Q buffer (block reads only its own Q tile
// into LDS before writing; disjoint regions across blocks).
// ---------------------------------------------------------------------------
__global__ __launch_bounds__(256) void attn_fwd(
    float* __restrict__ Q, const float* __restrict__ K, const float* __restrict__ V)
{
    const int bh = blockIdx.x;   // 0..31
    const int qt = blockIdx.y;   // 0..31
    const int q0 = qt * 64;

    float* Qg = Q + (size_t)bh * S_ * HD_;
    const float* Kg = K + (size_t)bh * S_ * HD_;
    const float* Vg = V + (size_t)bh * S_ * HD_;

    __shared__ float Qs[64][68];
    __shared__ float Ks[32][68];
    __shared__ float Vs[32][68];
    __shared__ float Ps[64][33];

    const int tid = threadIdx.x;
    const int r = tid >> 2;   // q row in tile
    const int g = tid & 3;    // column group
    const int qglob = q0 + r;

    // load Q tile (64x64): 4 float4 per thread
#pragma unroll
    for (int i = 0; i < 4; ++i) {
        const int idx = tid + i * 256;          // float4 index 0..1023
        const int qr = idx >> 4, qc = (idx & 15) * 4;
        *(float4*)&Qs[qr][qc] = *(const float4*)(Qg + (size_t)(q0 + qr) * HD_ + qc);
    }

    float mrun = -1e30f, lrun = 0.f;
    float Oa[16];
#pragma unroll
    for (int d = 0; d < 16; ++d) Oa[d] = 0.f;

    const int ntiles = 2 * (qt + 1);
    for (int t = 0; t < ntiles; ++t) {
        const int j0 = t * 32;
        __syncthreads();   // previous iteration's readers done (also covers Q-tile stores)
        // stage K,V tiles (32x64 each): 2 float4 per thread per matrix
#pragma unroll
        for (int i = 0; i < 2; ++i) {
            const int idx = tid + i * 256;      // float4 idx 0..511
            const int kr = idx >> 4, kc = (idx & 15) * 4;
            *(float4*)&Ks[kr][kc] = *(const float4*)(Kg + (size_t)(j0 + kr) * HD_ + kc);
            *(float4*)&Vs[kr][kc] = *(const float4*)(Vg + (size_t)(j0 + kr) * HD_ + kc);
        }
        __syncthreads();

        // scores for j = g + 4*jj
        float sc[8];
#pragma unroll
        for (int jj = 0; jj < 8; ++jj) sc[jj] = 0.f;
#pragma unroll
        for (int d4 = 0; d4 < 16; ++d4) {
            const float4 q4 = *(const float4*)&Qs[r][d4 * 4];
#pragma unroll
            for (int jj = 0; jj < 8; ++jj) {
                const float4 k4 = *(const float4*)&Ks[g + jj * 4][d4 * 4];
                sc[jj] += q4.x * k4.x + q4.y * k4.y + q4.z * k4.z + q4.w * k4.w;
            }
        }
        // mask + scale + row max
        float tmax = -1e30f;
#pragma unroll
        for (int jj = 0; jj < 8; ++jj) {
            const int kv = j0 + g + jj * 4;
            sc[jj] = (kv <= qglob) ? sc[jj] * SCALE : -1e30f;
            tmax = fmaxf(tmax, sc[jj]);
        }
        tmax = fmaxf(tmax, __shfl_xor(tmax, 1));
        tmax = fmaxf(tmax, __shfl_xor(tmax, 2));
        const float mnew  = fmaxf(mrun, tmax);
        const float alpha = __expf(mrun - mnew);
        float psum = 0.f;
#pragma unroll
        for (int jj = 0; jj < 8; ++jj) {
            const float p = __expf(sc[jj] - mnew);
            Ps[r][g + jj * 4] = p;
            psum += p;
        }
        psum += __shfl_xor(psum, 1);
        psum += __shfl_xor(psum, 2);
        lrun = alpha * lrun + psum;
        mrun = mnew;
        __syncthreads();   // Ps ready

        // O update: O[d] = alpha*O[d] + sum_j P[r][j] * V[j][d]
#pragma unroll
        for (int d = 0; d < 16; ++d) Oa[d] *= alpha;
#pragma unroll 4
        for (int j = 0; j < 32; ++j) {
            const float p = Ps[r][j];
#pragma unroll
            for (int dd = 0; dd < 4; ++dd) {
                const float4 v4 = *(const float4*)&Vs[j][g * 16 + dd * 4];
                Oa[dd * 4 + 0] += p * v4.x;
                Oa[dd * 4 + 1] += p * v4.y;
                Oa[dd * 4 + 2] += p * v4.z;
                Oa[dd * 4 + 3] += p * v4.w;
            }
        }
    }

    // write output back into Q buffer (head-major layout)
    const float inv = 1.f / lrun;
    float* orow = Qg + (size_t)qglob * HD_ + g * 16;
#pragma unroll
    for (int dd = 0; dd < 4; ++dd) {
        float4 ov;
        ov.x = Oa[dd * 4 + 0] * inv;
        ov.y = Oa[dd * 4 + 1] * inv;
        ov.z = Oa[dd * 4 + 2] * inv;
        ov.w = Oa[dd * 4 + 3] * inv;
        *(float4*)(orow + dd * 4) = ov;
    }
}

// ---------------------------------------------------------------------------
extern "C" void kernel_launch(void* const* d_in, const int* in_sizes, int n_in,
                              void* d_out, int out_size, void* d_ws, size_t ws_size,
                              hipStream_t stream)
{
    (void)in_sizes; (void)n_in; (void)out_size; (void)ws_size;
    const float* x     = (const float*)d_in[0];
    // d_in[1] = positions (== arange(S), unused: reference ignores it)
    const float* theta = (const float*)d_in[2];
    const float* Wq    = (const float*)d_in[3];
    const float* bq    = (const float*)d_in[4];
    const float* Wk    = (const float*)d_in[5];
    const float* bk    = (const float*)d_in[6];
    const float* Wv    = (const float*)d_in[7];
    const float* bv    = (const float*)d_in[8];
    const float* Wo    = (const float*)d_in[9];
    const float* bo    = (const float*)d_in[10];
    float* out = (float*)d_out;

    // workspace: q | k | v, each B*H*S*64 floats (16 MB) -> 48 MB total
    float* qws = (float*)d_ws;
    float* kws = qws + (size_t)B_ * H_ * S_ * HD_;
    float* vws = kws + (size_t)B_ * H_ * S_ * HD_;

    const dim3 gemmGrid(BS_ / 64, DIM_ / 64);
    const dim3 blk(256);

    // QKV projections -> head-major buffers
    gemm4096<<<gemmGrid, blk, 0, stream>>>(x, Wq, bq, qws, 0, 1);
    gemm4096<<<gemmGrid, blk, 0, stream>>>(x, Wk, bk, kws, 0, 1);
    gemm4096<<<gemmGrid, blk, 0, stream>>>(x, Wv, bv, vws, 0, 1);

    // RoPE in place on q, k
    const int ropeBlocks = (B_ * H_ * S_) / 8;
    rope_inplace<<<ropeBlocks, blk, 0, stream>>>(qws, theta);
    rope_inplace<<<ropeBlocks, blk, 0, stream>>>(kws, theta);

    // causal flash attention; output overwrites the Q buffer
    attn_fwd<<<dim3(B_ * H_, S_ / 64), blk, 0, stream>>>(qws, kws, vws);

    // output projection: read head-major attn output, write row-major d_out
    gemm4096<<<gemmGrid, blk, 0, stream>>>(qws, Wo, bo, out, 1, 0);
}

// Round 2
// 234.964 us; speedup vs baseline: 4.3168x; 4.3168x over previous
//
#include <hip/hip_runtime.h>
#include <math.h>

#define B_   2
#define S_   2048
#define DIM_ 1024
#define H_   16
#define HD_  64
#define BS_  (B_ * S_)              // 4096
#define CEXP 0.1803368801111244f    // log2(e) / sqrt(64)

typedef unsigned short u16;
typedef short s16x8 __attribute__((ext_vector_type(8)));
typedef float f32x4 __attribute__((ext_vector_type(4)));

#define MFMA16(a, b, c) __builtin_amdgcn_mfma_f32_16x16x32_bf16((a), (b), (c), 0, 0, 0)

__device__ __forceinline__ u16 f2bf(float f) {
    unsigned int u = __float_as_uint(f);
    u += 0x7fffu + ((u >> 16) & 1u);            // RNE
    return (u16)(u >> 16);
}
__device__ __forceinline__ float bf2f(u16 h) {
    return __uint_as_float(((unsigned int)h) << 16);
}

// ---------------------------------------------------------------------------
// x (fp32, 4096x1024) -> bf16, elementwise. 8 elems/thread.
// ---------------------------------------------------------------------------
__global__ __launch_bounds__(256) void cvt_x(const float* __restrict__ X,
                                             u16* __restrict__ Y)
{
    const int i = blockIdx.x * 256 + threadIdx.x;     // 0 .. 524287
    const float4 a = *(const float4*)(X + (size_t)i * 8);
    const float4 b = *(const float4*)(X + (size_t)i * 8 + 4);
    s16x8 o;
    o[0] = (short)f2bf(a.x); o[1] = (short)f2bf(a.y);
    o[2] = (short)f2bf(a.z); o[3] = (short)f2bf(a.w);
    o[4] = (short)f2bf(b.x); o[5] = (short)f2bf(b.y);
    o[6] = (short)f2bf(b.z); o[7] = (short)f2bf(b.w);
    *(s16x8*)(Y + (size_t)i * 8) = o;
}

// ---------------------------------------------------------------------------
// W (fp32, [K=1024][N=1024]) -> Wt (bf16, [N][K]).  32x32 LDS tile transpose.
// z selects which of the 4 weights.
// ---------------------------------------------------------------------------
__global__ __launch_bounds__(256) void wtrans4(
    const float* __restrict__ W0, const float* __restrict__ W1,
    const float* __restrict__ W2, const float* __restrict__ W3,
    u16* __restrict__ T0, u16* __restrict__ T1,
    u16* __restrict__ T2, u16* __restrict__ T3)
{
    const float* W; u16* T;
    switch (blockIdx.z) {
        case 0: W = W0; T = T0; break;
        case 1: W = W1; T = T1; break;
        case 2: W = W2; T = T2; break;
        default: W = W3; T = T3; break;
    }
    __shared__ float tile[32][33];
    const int n0 = blockIdx.x * 32, k0 = blockIdx.y * 32;
    const int c = threadIdx.x & 31, rr = threadIdx.x >> 5;   // 8 rows/pass
#pragma unroll
    for (int i = 0; i < 4; ++i) {
        const int k = rr + i * 8;
        tile[k][c] = W[(size_t)(k0 + k) * DIM_ + n0 + c];
    }
    __syncthreads();
#pragma unroll
    for (int i = 0; i < 4; ++i) {
        const int n = rr + i * 8;
        T[(size_t)(n0 + n) * DIM_ + k0 + c] = f2bf(tile[c][n]);
    }
}

// ---------------------------------------------------------------------------
// bf16 MFMA GEMM: Y[4096][1024] = A @ B (+bias), B given transposed [N][K].
// Tile 64x64, BK=64, 256 threads (4 waves, 2x2 wave grid, 32x32 each).
// HMIN: A is head-major [B][H][S][64];  HMOUT/OUTBF16: Y bf16 head-major.
// ---------------------------------------------------------------------------
template<int HMIN, int HMOUT, int OUTBF16>
__global__ __launch_bounds__(256) void gemm_mfma(
    const u16* __restrict__ A, const u16* __restrict__ Bt,
    const float* __restrict__ bias, void* __restrict__ Yv)
{
    __shared__ __align__(16) u16 As[64][72];
    __shared__ __align__(16) u16 Bs[64][72];

    const int tid = threadIdx.x;
    const int lane = tid & 63, wid = tid >> 6;
    const int l15 = lane & 15, lg = lane >> 4;
    const int row0 = blockIdx.x * 64, col0 = blockIdx.y * 64;
    const int wr = (wid >> 1) * 32, wc = (wid & 1) * 32;

    f32x4 acc[2][2];
#pragma unroll
    for (int m = 0; m < 2; ++m)
#pragma unroll
        for (int n = 0; n < 2; ++n) acc[m][n] = (f32x4){0.f, 0.f, 0.f, 0.f};

    for (int k0 = 0; k0 < DIM_; k0 += 64) {
        // stage A,B tiles: 512 chunks of 16B each, 2 per thread per matrix
#pragma unroll
        for (int it = 0; it < 2; ++it) {
            const int idx = it * 256 + tid;        // 0..511
            const int r = idx >> 3, cg = (idx & 7) * 8;
            size_t aaddr;
            if (HMIN) {   // k0 multiple of 64 -> one head per K-step
                const int rr = row0 + r;
                aaddr = (((size_t)(rr >> 11) * H_ + (k0 >> 6)) * S_ + (rr & (S_ - 1))) * HD_ + cg;
            } else {
                aaddr = (size_t)(row0 + r) * DIM_ + k0 + cg;
            }
            *(s16x8*)&As[r][cg] = *(const s16x8*)(A + aaddr);
            *(s16x8*)&Bs[r][cg] = *(const s16x8*)(Bt + (size_t)(col0 + r) * DIM_ + k0 + cg);
        }
        __syncthreads();

        s16x8 af[2][2], bfr[2][2];
#pragma unroll
        for (int m = 0; m < 2; ++m)
#pragma unroll
            for (int kf = 0; kf < 2; ++kf)
                af[m][kf] = *(const s16x8*)&As[wr + m * 16 + l15][kf * 32 + lg * 8];
#pragma unroll
        for (int n = 0; n < 2; ++n)
#pragma unroll
            for (int kf = 0; kf < 2; ++kf)
                bfr[n][kf] = *(const s16x8*)&Bs[wc + n * 16 + l15][kf * 32 + lg * 8];
#pragma unroll
        for (int m = 0; m < 2; ++m)
#pragma unroll
            for (int n = 0; n < 2; ++n) {
                acc[m][n] = MFMA16(af[m][0], bfr[n][0], acc[m][n]);
                acc[m][n] = MFMA16(af[m][1], bfr[n][1], acc[m][n]);
            }
        __syncthreads();
    }

    // epilogue: C row = row0+wr+m*16+lg*4+r, col = col0+wc+n*16+l15
#pragma unroll
    for (int n = 0; n < 2; ++n) {
        const int cc = col0 + wc + n * 16 + l15;
        const float bv = bias[cc];
#pragma unroll
        for (int m = 0; m < 2; ++m)
#pragma unroll
            for (int r = 0; r < 4; ++r) {
                const int rr = row0 + wr + m * 16 + lg * 4 + r;
                const float val = acc[m][n][r] + bv;
                if (OUTBF16) {
                    u16* Y = (u16*)Yv;
                    size_t addr;
                    if (HMOUT)
                        addr = (((size_t)(rr >> 11) * H_ + (cc >> 6)) * S_ + (rr & (S_ - 1))) * HD_ + (cc & 63);
                    else
                        addr = (size_t)rr * DIM_ + cc;
                    Y[addr] = f2bf(val);
                } else {
                    ((float*)Yv)[(size_t)rr * DIM_ + cc] = val;
                }
            }
    }
}

// ---------------------------------------------------------------------------
// RoPE in place on bf16 [B*H][S][64]; z selects q (0) or k (1).
// ---------------------------------------------------------------------------
__global__ __launch_bounds__(256) void rope2(u16* __restrict__ Tq, u16* __restrict__ Tk,
                                             const float* __restrict__ theta)
{
    u16* T = blockIdx.z ? Tk : Tq;
    const int row = blockIdx.x * 8 + (threadIdx.x >> 5);
    const int j   = threadIdx.x & 31;
    const int s   = row & (S_ - 1);
    u16* rp = T + (size_t)row * HD_;
    const unsigned int pr = *(const unsigned int*)(rp + 2 * j);
    const float x1 = bf2f((u16)(pr & 0xffffu));
    const float x2 = bf2f((u16)(pr >> 16));
    float sn, cs;
    sincosf((float)s * theta[j], &sn, &cs);
    const u16 o1 = f2bf(x1 * cs - x2 * sn);
    const u16 o2 = f2bf(x1 * sn + x2 * cs);
    rp[j]      = o1;    // wave-internal: all loads complete before stores
    rp[32 + j] = o2;
}

// ---------------------------------------------------------------------------
// bf16 MFMA causal flash attention.
// Grid (32 heads, 32 q-tiles remapped). 256 threads = 4 waves.
// Wave w owns q rows q0 + w*16 .. +15. KV tiles of 64.
// Per KV tile per wave: 8 MFMA QK^T + 8 MFMA PV. Output in place into Q.
// ---------------------------------------------------------------------------
__global__ __launch_bounds__(256) void attn_mfma(
    u16* __restrict__ Q, const u16* __restrict__ K, const u16* __restrict__ V)
{
    const int bh = blockIdx.x;
    const int y  = blockIdx.y;
    const int qt = (y & 1) ? (31 - (y >> 1)) : (y >> 1);   // balance dispatch
    const int q0 = qt * 64;

    u16* Qg = Q + (size_t)bh * S_ * HD_;
    const u16* Kg = K + (size_t)bh * S_ * HD_;
    const u16* Vg = V + (size_t)bh * S_ * HD_;

    __shared__ __align__(16) u16 Ks[64][72];
    __shared__ __align__(16) u16 Vt[64][72];      // V transposed: Vt[d][kv]
    __shared__ __align__(16) u16 Ps[4][16][72];   // per-wave P tile

    const int tid = threadIdx.x;
    const int wid = tid >> 6, lane = tid & 63;
    const int l15 = lane & 15, lg = lane >> 4;

    // Q fragments (held in registers for the whole block): rows wid*16+l15
    s16x8 qf[2];
    {
        const u16* qrow = Qg + (size_t)(q0 + wid * 16 + l15) * HD_ + lg * 8;
        qf[0] = *(const s16x8*)(qrow);
        qf[1] = *(const s16x8*)(qrow + 32);
    }

    f32x4 o[4];
#pragma unroll
    for (int n = 0; n < 4; ++n) o[n] = (f32x4){0.f, 0.f, 0.f, 0.f};
    float m_i[4], l_i[4];
#pragma unroll
    for (int r = 0; r < 4; ++r) { m_i[r] = -1e30f; l_i[r] = 0.f; }

    for (int t = 0; t <= qt; ++t) {
        const int j0t = t * 64;
        __syncthreads();   // previous tile fully consumed
        // stage K tile [64][64] and V^T tile
#pragma unroll
        for (int it = 0; it < 2; ++it) {
            const int idx = it * 256 + tid;       // 0..511
            const int r = idx >> 3, cg = (idx & 7) * 8;
            *(s16x8*)&Ks[r][cg] = *(const s16x8*)(Kg + (size_t)(j0t + r) * HD_ + cg);
            const s16x8 vv = *(const s16x8*)(Vg + (size_t)(j0t + r) * HD_ + cg);
#pragma unroll
            for (int j = 0; j < 8; ++j) Vt[cg + j][r] = (u16)vv[j];
        }
        __syncthreads();

        // ---- QK^T: sc[n][r] = S[q = q0+wid*16+lg*4+r][kv = j0t+n*16+l15]
        f32x4 sc[4];
#pragma unroll
        for (int n = 0; n < 4; ++n) {
            sc[n] = (f32x4){0.f, 0.f, 0.f, 0.f};
            const s16x8 kf0 = *(const s16x8*)&Ks[n * 16 + l15][lg * 8];
            const s16x8 kf1 = *(const s16x8*)&Ks[n * 16 + l15][lg * 8 + 32];
            sc[n] = MFMA16(qf[0], kf0, sc[n]);
            sc[n] = MFMA16(qf[1], kf1, sc[n]);
        }
        if (t == qt) {   // diagonal tile: mask kv > q
#pragma unroll
            for (int n = 0; n < 4; ++n)
#pragma unroll
                for (int r = 0; r < 4; ++r)
                    if (n * 16 + l15 > wid * 16 + lg * 4 + r) sc[n][r] = -1e30f;
        }

        // ---- online softmax (per lane: 4 q-rows)
        float alpha[4];
#pragma unroll
        for (int r = 0; r < 4; ++r) {
            float rm = fmaxf(fmaxf(sc[0][r], sc[1][r]), fmaxf(sc[2][r], sc[3][r]));
            rm = fmaxf(rm, __shfl_xor(rm, 1));
            rm = fmaxf(rm, __shfl_xor(rm, 2));
            rm = fmaxf(rm, __shfl_xor(rm, 4));
            rm = fmaxf(rm, __shfl_xor(rm, 8));
            const float mn = fmaxf(m_i[r], rm);
            alpha[r] = exp2f((m_i[r] - mn) * CEXP);
            m_i[r] = mn;
            float p0 = exp2f((sc[0][r] - mn) * CEXP);
            float p1 = exp2f((sc[1][r] - mn) * CEXP);
            float p2 = exp2f((sc[2][r] - mn) * CEXP);
            float p3 = exp2f((sc[3][r] - mn) * CEXP);
            const int pr = lg * 4 + r;
            Ps[wid][pr][ 0 + l15] = f2bf(p0);
            Ps[wid][pr][16 + l15] = f2bf(p1);
            Ps[wid][pr][32 + l15] = f2bf(p2);
            Ps[wid][pr][48 + l15] = f2bf(p3);
            float ps = (p0 + p1) + (p2 + p3);
            ps += __shfl_xor(ps, 1);
            ps += __shfl_xor(ps, 2);
            ps += __shfl_xor(ps, 4);
            ps += __shfl_xor(ps, 8);
            l_i[r] = l_i[r] * alpha[r] + ps;
        }
#pragma unroll
        for (int n = 0; n < 4; ++n)
#pragma unroll
            for (int r = 0; r < 4; ++r) o[n][r] *= alpha[r];

        // ---- PV: O[q][d] += P[q][kv] @ V[kv][d]   (intra-wave LDS dependency)
#pragma unroll
        for (int kf = 0; kf < 2; ++kf) {
            const s16x8 pf = *(const s16x8*)&Ps[wid][l15][kf * 32 + lg * 8];
#pragma unroll
            for (int n = 0; n < 4; ++n) {
                const s16x8 vf = *(const s16x8*)&Vt[n * 16 + l15][kf * 32 + lg * 8];
                o[n] = MFMA16(pf, vf, o[n]);
            }
        }
    }

    // ---- epilogue: O / l, write bf16 in place into Q buffer
    float inv[4];
#pragma unroll
    for (int r = 0; r < 4; ++r) inv[r] = 1.f / l_i[r];
#pragma unroll
    for (int n = 0; n < 4; ++n)
#pragma unroll
        for (int r = 0; r < 4; ++r)
            Qg[(size_t)(q0 + wid * 16 + lg * 4 + r) * HD_ + n * 16 + l15] =
                f2bf(o[n][r] * inv[r]);
}

// ---------------------------------------------------------------------------
extern "C" void kernel_launch(void* const* d_in, const int* in_sizes, int n_in,
                              void* d_out, int out_size, void* d_ws, size_t ws_size,
                              hipStream_t stream)
{
    (void)in_sizes; (void)n_in; (void)out_size; (void)ws_size;
    const float* x     = (const float*)d_in[0];
    const float* theta = (const float*)d_in[2];
    const float* Wq    = (const float*)d_in[3];
    const float* bq    = (const float*)d_in[4];
    const float* Wk    = (const float*)d_in[5];
    const float* bk    = (const float*)d_in[6];
    const float* Wv    = (const float*)d_in[7];
    const float* bv    = (const float*)d_in[8];
    const float* Wo    = (const float*)d_in[9];
    const float* bo    = (const float*)d_in[10];
    float* out = (float*)d_out;

    // ws layout (u16): xb[4M] | Wt q,k,v,o [1M each] | q[4M] | k[4M] | v[4M]
    u16* xb  = (u16*)d_ws;
    u16* wtq = xb + (size_t)BS_ * DIM_;
    u16* wtk = wtq + (size_t)DIM_ * DIM_;
    u16* wtv = wtk + (size_t)DIM_ * DIM_;
    u16* wto = wtv + (size_t)DIM_ * DIM_;
    u16* qws = wto + (size_t)DIM_ * DIM_;
    u16* kws = qws + (size_t)B_ * H_ * S_ * HD_;
    u16* vws = kws + (size_t)B_ * H_ * S_ * HD_;

    const dim3 blk(256);

    cvt_x<<<dim3(BS_ * DIM_ / 8 / 256), blk, 0, stream>>>(x, xb);
    wtrans4<<<dim3(32, 32, 4), blk, 0, stream>>>(Wq, Wk, Wv, Wo, wtq, wtk, wtv, wto);

    const dim3 gg(BS_ / 64, DIM_ / 64);
    gemm_mfma<0, 1, 1><<<gg, blk, 0, stream>>>(xb, wtq, bq, qws);
    gemm_mfma<0, 1, 1><<<gg, blk, 0, stream>>>(xb, wtk, bk, kws);
    gemm_mfma<0, 1, 1><<<gg, blk, 0, stream>>>(xb, wtv, bv, vws);

    rope2<<<dim3(B_ * H_ * S_ / 8, 1, 2), blk, 0, stream>>>(qws, kws, theta);

    attn_mfma<<<dim3(B_ * H_, S_ / 64), blk, 0, stream>>>(qws, kws, vws);

    gemm_mfma<1, 0, 0><<<gg, blk, 0, stream>>>(qws, wto, bo, out);
}

// Round 3
// 197.541 us; speedup vs baseline: 5.1345x; 1.1894x over previous
//
#include <hip/hip_runtime.h>
#include <math.h>

#define B_   2
#define S_   2048
#define DIM_ 1024
#define H_   16
#define HD_  64
#define BS_  (B_ * S_)              // 4096
#define BHSD ((size_t)B_ * H_ * S_ * HD_)   // 4M elements
#define CEXP 0.1803368801111244f    // log2(e) / sqrt(64)

typedef unsigned short u16;
typedef short s16x8 __attribute__((ext_vector_type(8)));
typedef float f32x4 __attribute__((ext_vector_type(4)));

#define MFMA16(a, b, c) __builtin_amdgcn_mfma_f32_16x16x32_bf16((a), (b), (c), 0, 0, 0)

__device__ __forceinline__ u16 f2bf(float f) {
    unsigned int u = __float_as_uint(f);
    u += 0x7fffu + ((u >> 16) & 1u);            // RNE
    return (u16)(u >> 16);
}
__device__ __forceinline__ float bf2f(u16 h) {
    return __uint_as_float(((unsigned int)h) << 16);
}
__device__ __forceinline__ unsigned int cvt_pk_bf16(float a, float b) {
    unsigned int r;
    asm("v_cvt_pk_bf16_f32 %0, %1, %2" : "=v"(r) : "v"(a), "v"(b));
    return r;
}
// async global->LDS, 16B per lane; LDS dest = base + lane*16 (wave-uniform base)
__device__ __forceinline__ void gl16(void* lds, const void* g) {
    __builtin_amdgcn_global_load_lds(
        (__attribute__((address_space(1))) void*)(g),
        (__attribute__((address_space(3))) void*)(lds), 16, 0, 0);
}

// ---------------------------------------------------------------------------
// x (fp32, 4096x1024) -> bf16
// ---------------------------------------------------------------------------
__global__ __launch_bounds__(256) void cvt_x(const float* __restrict__ X,
                                             u16* __restrict__ Y)
{
    const int i = blockIdx.x * 256 + threadIdx.x;
    const float4 a = *(const float4*)(X + (size_t)i * 8);
    const float4 b = *(const float4*)(X + (size_t)i * 8 + 4);
    s16x8 o;
    o[0] = (short)f2bf(a.x); o[1] = (short)f2bf(a.y);
    o[2] = (short)f2bf(a.z); o[3] = (short)f2bf(a.w);
    o[4] = (short)f2bf(b.x); o[5] = (short)f2bf(b.y);
    o[6] = (short)f2bf(b.z); o[7] = (short)f2bf(b.w);
    *(s16x8*)(Y + (size_t)i * 8) = o;
}

// ---------------------------------------------------------------------------
// W (fp32 [K][N]) -> Wt (bf16 [N][K]); z selects weight. 32x32 LDS transpose.
// ---------------------------------------------------------------------------
__global__ __launch_bounds__(256) void wtrans4(
    const float* __restrict__ W0, const float* __restrict__ W1,
    const float* __restrict__ W2, const float* __restrict__ W3,
    u16* __restrict__ T0, u16* __restrict__ T1,
    u16* __restrict__ T2, u16* __restrict__ T3)
{
    const float* W; u16* T;
    switch (blockIdx.z) {
        case 0: W = W0; T = T0; break;
        case 1: W = W1; T = T1; break;
        case 2: W = W2; T = T2; break;
        default: W = W3; T = T3; break;
    }
    __shared__ float tile[32][33];
    const int n0 = blockIdx.x * 32, k0 = blockIdx.y * 32;
    const int c = threadIdx.x & 31, rr = threadIdx.x >> 5;
#pragma unroll
    for (int i = 0; i < 4; ++i) {
        const int k = rr + i * 8;
        tile[k][c] = W[(size_t)(k0 + k) * DIM_ + n0 + c];
    }
    __syncthreads();
#pragma unroll
    for (int i = 0; i < 4; ++i) {
        const int n = rr + i * 8;
        T[(size_t)(n0 + n) * DIM_ + k0 + c] = f2bf(tile[c][n]);
    }
}

// ---------------------------------------------------------------------------
// concat biases: bias3[0:1024)=bq, [1024:2048)=bk, [2048:3072)=bv
// ---------------------------------------------------------------------------
__global__ __launch_bounds__(256) void cat_bias(
    const float* __restrict__ q, const float* __restrict__ k,
    const float* __restrict__ v, float* __restrict__ o)
{
    const int i = blockIdx.x * 256 + threadIdx.x;   // grid 12 -> 3072
    o[i] = (i < 1024) ? q[i] : ((i < 2048) ? k[i - 1024] : v[i - 2048]);
}

// ---------------------------------------------------------------------------
// bf16 MFMA GEMM, tile 128 x BN, BK=64, 256 threads (4 waves, 2x2 quadrants).
// A,Bt staged via global_load_lds (16B) into linear LDS, XOR-swizzled via
// pre-swizzled global source: phys_byte = row*128B + (colb ^ ((row&7)<<4)).
// HMIN: A is head-major [B][H][S][64].
// EPI 0: bf16 head-major out into contiguous q|k|v (col/1024 selects buffer).
// EPI 1: fp32 row-major out.
// ---------------------------------------------------------------------------
template<int BN, int HMIN, int EPI>
__global__ __launch_bounds__(256, 3) void gemm_mfma(
    const u16* __restrict__ A, const u16* __restrict__ Bt,
    const float* __restrict__ bias, void* __restrict__ Yv)
{
    __shared__ u16 As[128 * 64];
    __shared__ u16 Bs[BN * 64];

    const int tid = threadIdx.x, lane = tid & 63, wid = tid >> 6;
    const int l15 = lane & 15, lg = lane >> 4;
    const int row0 = blockIdx.x * 128, col0 = blockIdx.y * BN;
    const int wr = (wid >> 1) * 64;
    const int wc = (wid & 1) * (BN / 2);
    constexpr int NM = 4, NN = BN / 32, BCH = BN / 32;

    const int l8 = lane >> 3, l7 = lane & 7;
    const int colE = ((l7 ^ l8) << 3);          // k-element offset (swizzled)

    const u16* aptr[4]; u16* aldp[4];
#pragma unroll
    for (int i = 0; i < 4; ++i) {
        const int ci = wid * 4 + i;
        const int rr = row0 + ci * 8 + l8;
        size_t a0;
        if (HMIN)
            a0 = (((size_t)(rr >> 11) * H_) * S_ + (rr & (S_ - 1))) * HD_ + colE;
        else
            a0 = (size_t)rr * DIM_ + colE;
        aptr[i] = A + a0;
        aldp[i] = As + ci * 512;
    }
    const u16* bptr[BCH]; u16* bldp[BCH];
#pragma unroll
    for (int i = 0; i < BCH; ++i) {
        const int ci = wid * BCH + i;
        const int rr = col0 + ci * 8 + l8;
        bptr[i] = Bt + (size_t)rr * DIM_ + colE;
        bldp[i] = Bs + ci * 512;
    }
    const size_t astep = HMIN ? (size_t)S_ * HD_ : 64;

    f32x4 acc[NM][NN];
#pragma unroll
    for (int m = 0; m < NM; ++m)
#pragma unroll
        for (int n = 0; n < NN; ++n) acc[m][n] = (f32x4){0.f, 0.f, 0.f, 0.f};

    for (int k0 = 0; k0 < DIM_; k0 += 64) {
        __syncthreads();   // previous frag reads done
#pragma unroll
        for (int i = 0; i < 4; ++i) gl16(aldp[i], aptr[i]);
#pragma unroll
        for (int i = 0; i < BCH; ++i) gl16(bldp[i], bptr[i]);
#pragma unroll
        for (int i = 0; i < 4; ++i) aptr[i] += astep;
#pragma unroll
        for (int i = 0; i < BCH; ++i) bptr[i] += 64;
        __syncthreads();   // loads drained (compiler emits vmcnt(0))

        s16x8 af[NM][2], bfr[NN][2];
#pragma unroll
        for (int m = 0; m < NM; ++m) {
            const int row = wr + m * 16 + l15;
#pragma unroll
            for (int kf = 0; kf < 2; ++kf)
                af[m][kf] = *(const s16x8*)&As[row * 64 +
                    (((kf * 64 + lg * 16) ^ ((l15 & 7) << 4)) >> 1)];
        }
#pragma unroll
        for (int n = 0; n < NN; ++n) {
            const int row = wc + n * 16 + l15;
#pragma unroll
            for (int kf = 0; kf < 2; ++kf)
                bfr[n][kf] = *(const s16x8*)&Bs[row * 64 +
                    (((kf * 64 + lg * 16) ^ ((l15 & 7) << 4)) >> 1)];
        }
#pragma unroll
        for (int m = 0; m < NM; ++m)
#pragma unroll
            for (int n = 0; n < NN; ++n) {
                acc[m][n] = MFMA16(af[m][0], bfr[n][0], acc[m][n]);
                acc[m][n] = MFMA16(af[m][1], bfr[n][1], acc[m][n]);
            }
    }

    // epilogue
#pragma unroll
    for (int n = 0; n < NN; ++n) {
        const int cc = col0 + wc + n * 16 + l15;
        const float bv = bias[cc];
#pragma unroll
        for (int m = 0; m < NM; ++m)
#pragma unroll
            for (int r = 0; r < 4; ++r) {
                const int rr = row0 + wr + m * 16 + lg * 4 + r;
                const float val = acc[m][n][r] + bv;
                if (EPI == 0) {
                    u16* Y = (u16*)Yv;
                    const int which = cc >> 10, h = (cc >> 6) & (H_ - 1), d = cc & 63;
                    const size_t dst = (size_t)which * BHSD
                        + (((size_t)(rr >> 11) * H_ + h) * S_ + (rr & (S_ - 1))) * HD_ + d;
                    Y[dst] = f2bf(val);
                } else {
                    ((float*)Yv)[(size_t)rr * DIM_ + cc] = val;
                }
            }
    }
}

// ---------------------------------------------------------------------------
// RoPE in place on bf16 [B*H][S][64]; z selects q (0) or k (1).
// ---------------------------------------------------------------------------
__global__ __launch_bounds__(256) void rope2(u16* __restrict__ Tq, u16* __restrict__ Tk,
                                             const float* __restrict__ theta)
{
    u16* T = blockIdx.z ? Tk : Tq;
    const int row = blockIdx.x * 8 + (threadIdx.x >> 5);
    const int j   = threadIdx.x & 31;
    const int s   = row & (S_ - 1);
    u16* rp = T + (size_t)row * HD_;
    const unsigned int pr = *(const unsigned int*)(rp + 2 * j);
    const float x1 = bf2f((u16)(pr & 0xffffu));
    const float x2 = bf2f((u16)(pr >> 16));
    float sn, cs;
    sincosf((float)s * theta[j], &sn, &cs);
    const u16 o1 = f2bf(x1 * cs - x2 * sn);
    const u16 o2 = f2bf(x1 * sn + x2 * cs);
    rp[j]      = o1;    // wave-internal: loads complete before stores
    rp[32 + j] = o2;
}

// ---------------------------------------------------------------------------
// V [bh][s][64] -> VT [bh][64][s]  (64 x 64 LDS tile transpose)
// ---------------------------------------------------------------------------
__global__ __launch_bounds__(256) void vtrans(const u16* __restrict__ V,
                                              u16* __restrict__ VT)
{
    __shared__ u16 t[64][72];
    const int bh = blockIdx.y, s0 = blockIdx.x * 64;
    const int tid = threadIdx.x;
#pragma unroll
    for (int i = 0; i < 2; ++i) {
        const int idx = i * 256 + tid;
        const int r = idx >> 3, c = (idx & 7) * 8;
        *(s16x8*)&t[r][c] = *(const s16x8*)(V + ((size_t)bh * S_ + s0 + r) * HD_ + c);
    }
    __syncthreads();
    const int d = tid >> 2, sc0 = (tid & 3) * 16;
    u16 tmp[16];
#pragma unroll
    for (int j = 0; j < 16; ++j) tmp[j] = t[sc0 + j][d];
    u16* dst = VT + ((size_t)bh * HD_ + d) * S_ + s0 + sc0;
    *(s16x8*)dst = *(s16x8*)tmp;
    *(s16x8*)(dst + 8) = *(s16x8*)(tmp + 8);
}

// ---------------------------------------------------------------------------
// bf16 MFMA causal flash attention, KV tile = 128.
// Grid (32 q-tiles zigzag, 32 bh). 256 threads = 4 waves, wave w: q rows w*16..+15.
// K staged swizzled ((row&7)<<4 within 128B rows); VT staged swizzled
// ((row&15)<<4 within 256B rows); both via global_load_lds.
// Output written in place into Q.
// ---------------------------------------------------------------------------
__global__ __launch_bounds__(256, 3) void attn_mfma(
    u16* __restrict__ Q, const u16* __restrict__ K, const u16* __restrict__ VT)
{
    const int y = blockIdx.x;
    const int qt = (y & 1) ? (31 - (y >> 1)) : (y >> 1);
    const int bh = blockIdx.y;
    const int q0 = qt * 64;

    u16* Qg = Q + (size_t)bh * S_ * HD_;
    const u16* Kg = K + (size_t)bh * S_ * HD_;
    const u16* Vg = VT + (size_t)bh * HD_ * S_;   // [64][2048]

    __shared__ u16 Ks[128 * 64];       // 16 KB
    __shared__ u16 Vs[64 * 128];       // 16 KB (V^T tile)
    __shared__ u16 Ps[4][16][136];     // 17 KB, per-wave P

    const int tid = threadIdx.x, wid = tid >> 6, lane = tid & 63;
    const int l15 = lane & 15, lg = lane >> 4;
    const int l8 = lane >> 3, l7 = lane & 7;

    // Q fragments (rows q0 + wid*16 + l15), post-RoPE
    s16x8 qf[2];
    {
        const u16* qrow = Qg + (size_t)(q0 + wid * 16 + l15) * HD_ + lg * 8;
        qf[0] = *(const s16x8*)(qrow);
        qf[1] = *(const s16x8*)(qrow + 32);
    }

    // staging pointers (4 K-chunks + 4 V-chunks per wave)
    const u16* kptr[4]; u16* kldp[4];
    const u16* vptr[4]; u16* vldp[4];
#pragma unroll
    for (int i = 0; i < 4; ++i) {
        const int ci = wid * 4 + i;
        kptr[i] = Kg + (size_t)(ci * 8 + l8) * HD_ + ((l7 ^ l8) << 3);
        kldp[i] = Ks + ci * 512;
        const int vrow = ci * 4 + (lane >> 4);
        const int vcol = (((lane & 15) ^ (vrow & 15)) << 3);
        vptr[i] = Vg + (size_t)vrow * S_ + vcol;
        vldp[i] = Vs + ci * 512;
    }

    f32x4 o[4];
#pragma unroll
    for (int n = 0; n < 4; ++n) o[n] = (f32x4){0.f, 0.f, 0.f, 0.f};
    float m_i[4], l_i[4];
#pragma unroll
    for (int r = 0; r < 4; ++r) { m_i[r] = -1e30f; l_i[r] = 0.f; }

    const int nt = (qt + 2) >> 1;
    for (int t = 0; t < nt; ++t) {
        const int j0 = t * 128;
        const int kvlim = (q0 + 64 - j0 < 128) ? 64 : 128;   // 64 or 128 only
        const bool lastt = (t == nt - 1);

        __syncthreads();   // previous chunk fully consumed
#pragma unroll
        for (int i = 0; i < 4; ++i) gl16(kldp[i], kptr[i]);
#pragma unroll
        for (int i = 0; i < 4; ++i) gl16(vldp[i], vptr[i]);
#pragma unroll
        for (int i = 0; i < 4; ++i) { kptr[i] += 128 * HD_; vptr[i] += 128; }
        __syncthreads();   // staged (vmcnt drained before barrier)

        // ---- QK^T: sc[n][r] = S[q0+wid*16+lg*4+r][j0+n*16+l15]
        f32x4 sc[8];
#pragma unroll
        for (int n = 0; n < 8; ++n) {
            sc[n] = (f32x4){0.f, 0.f, 0.f, 0.f};
            if (n * 16 < kvlim) {
                const int row = n * 16 + l15;
                const int swz = (l15 & 7) << 4;
                const s16x8 kf0 = *(const s16x8*)&Ks[row * 64 + (((lg * 16) ^ swz) >> 1)];
                const s16x8 kf1 = *(const s16x8*)&Ks[row * 64 + (((64 + lg * 16) ^ swz) >> 1)];
                sc[n] = MFMA16(qf[0], kf0, sc[n]);
                sc[n] = MFMA16(qf[1], kf1, sc[n]);
            }
        }
        if (lastt) {
            const int qbase = q0 + wid * 16 + lg * 4;
#pragma unroll
            for (int n = 0; n < 8; ++n) if (n * 16 < kvlim) {
                const int kvg = j0 + n * 16 + l15;
#pragma unroll
                for (int r = 0; r < 4; ++r)
                    if (kvg > qbase + r) sc[n][r] = -1e30f;
            }
        }

        // ---- online softmax (per lane: 4 q rows)
        float alpha[4];
#pragma unroll
        for (int r = 0; r < 4; ++r) {
            float rm = -1e30f;
#pragma unroll
            for (int n = 0; n < 8; ++n) if (n * 16 < kvlim) rm = fmaxf(rm, sc[n][r]);
            rm = fmaxf(rm, __shfl_xor(rm, 1));
            rm = fmaxf(rm, __shfl_xor(rm, 2));
            rm = fmaxf(rm, __shfl_xor(rm, 4));
            rm = fmaxf(rm, __shfl_xor(rm, 8));
            const float mn = fmaxf(m_i[r], rm);
            alpha[r] = exp2f((m_i[r] - mn) * CEXP);
            m_i[r] = mn;
            float p[8]; float ps = 0.f;
#pragma unroll
            for (int n = 0; n < 8; ++n) if (n * 16 < kvlim) {
                p[n] = exp2f((sc[n][r] - mn) * CEXP);
                ps += p[n];
            }
            const int pr = lg * 4 + r;
#pragma unroll
            for (int np = 0; np < 4; ++np) if (np * 32 < kvlim) {
                const unsigned int pk = cvt_pk_bf16(p[2 * np], p[2 * np + 1]);
                Ps[wid][pr][(2 * np) * 16 + l15]     = (u16)(pk & 0xffffu);
                Ps[wid][pr][(2 * np + 1) * 16 + l15] = (u16)(pk >> 16);
            }
            ps += __shfl_xor(ps, 1);
            ps += __shfl_xor(ps, 2);
            ps += __shfl_xor(ps, 4);
            ps += __shfl_xor(ps, 8);
            l_i[r] = l_i[r] * alpha[r] + ps;
        }
#pragma unroll
        for (int n = 0; n < 4; ++n)
#pragma unroll
            for (int r = 0; r < 4; ++r) o[n][r] *= alpha[r];

        // ---- PV: O[q][d] += P[q][kv] @ V^T[d][kv]  (intra-wave LDS dep)
#pragma unroll
        for (int kf = 0; kf < 4; ++kf) if (kf * 32 < kvlim) {
            const s16x8 pf = *(const s16x8*)&Ps[wid][l15][kf * 32 + lg * 8];
#pragma unroll
            for (int n = 0; n < 4; ++n) {
                const int row = n * 16 + l15;
                const s16x8 vf = *(const s16x8*)&Vs[row * 128 +
                    (((kf * 64 + lg * 16) ^ (l15 << 4)) >> 1)];
                o[n] = MFMA16(pf, vf, o[n]);
            }
        }
    }

    // ---- epilogue: O / l, write bf16 in place into Q
    float inv[4];
#pragma unroll
    for (int r = 0; r < 4; ++r) inv[r] = 1.f / l_i[r];
#pragma unroll
    for (int n = 0; n < 4; ++n)
#pragma unroll
        for (int r = 0; r < 4; ++r)
            Qg[(size_t)(q0 + wid * 16 + lg * 4 + r) * HD_ + n * 16 + l15] =
                f2bf(o[n][r] * inv[r]);
}

// ---------------------------------------------------------------------------
extern "C" void kernel_launch(void* const* d_in, const int* in_sizes, int n_in,
                              void* d_out, int out_size, void* d_ws, size_t ws_size,
                              hipStream_t stream)
{
    (void)in_sizes; (void)n_in; (void)out_size; (void)ws_size;
    const float* x     = (const float*)d_in[0];
    const float* theta = (const float*)d_in[2];
    const float* Wq    = (const float*)d_in[3];
    const float* bq    = (const float*)d_in[4];
    const float* Wk    = (const float*)d_in[5];
    const float* bk    = (const float*)d_in[6];
    const float* Wv    = (const float*)d_in[7];
    const float* bv    = (const float*)d_in[8];
    const float* Wo    = (const float*)d_in[9];
    const float* bo    = (const float*)d_in[10];
    float* out = (float*)d_out;

    // ws (u16 units): xb 4M | wtq|wtk|wtv 3M | wto 1M | q|k|v 4M each | bias3
    u16* xb  = (u16*)d_ws;
    u16* wtq = xb + (size_t)BS_ * DIM_;
    u16* wtk = wtq + (size_t)DIM_ * DIM_;
    u16* wtv = wtk + (size_t)DIM_ * DIM_;
    u16* wto = wtv + (size_t)DIM_ * DIM_;
    u16* qws = wto + (size_t)DIM_ * DIM_;
    u16* kws = qws + BHSD;
    u16* vws = kws + BHSD;
    float* bias3 = (float*)(vws + BHSD);
    u16* vt = xb;                     // reuse xb after the QKV GEMM

    const dim3 blk(256);

    cvt_x<<<dim3(BS_ * DIM_ / 8 / 256), blk, 0, stream>>>(x, xb);
    wtrans4<<<dim3(32, 32, 4), blk, 0, stream>>>(Wq, Wk, Wv, Wo, wtq, wtk, wtv, wto);
    cat_bias<<<dim3(12), blk, 0, stream>>>(bq, bk, bv, bias3);

    // fused QKV projection: A[4096x1024] @ [Wq|Wk|Wv]^T (N=3072)
    gemm_mfma<128, 0, 0><<<dim3(32, 24), blk, 0, stream>>>(xb, wtq, bias3, qws);

    rope2<<<dim3(B_ * H_ * S_ / 8, 1, 2), blk, 0, stream>>>(qws, kws, theta);
    vtrans<<<dim3(32, 32), blk, 0, stream>>>(vws, vt);

    attn_mfma<<<dim3(32, 32), blk, 0, stream>>>(qws, kws, vt);

    // output projection (head-major A in, fp32 row-major out)
    gemm_mfma<64, 1, 1><<<dim3(32, 16), blk, 0, stream>>>(qws, wto, bo, out);
}

// Round 4
// 150.229 us; speedup vs baseline: 6.7516x; 1.3149x over previous
//
#include <hip/hip_runtime.h>
#include <math.h>

#define B_   2
#define S_   2048
#define DIM_ 1024
#define H_   16
#define HD_  64
#define BS_  (B_ * S_)              // 4096
#define BHSD ((size_t)B_ * H_ * S_ * HD_)   // 4M elements
#define CEXP 0.1803368801111244f    // log2(e) / sqrt(64)

typedef unsigned short u16;
typedef short s16x8 __attribute__((ext_vector_type(8)));
typedef float f32x4 __attribute__((ext_vector_type(4)));
typedef float f32x16 __attribute__((ext_vector_type(16)));

#define MFMA16(a, b, c) __builtin_amdgcn_mfma_f32_16x16x32_bf16((a), (b), (c), 0, 0, 0)
#define MFMA32(a, b, c) __builtin_amdgcn_mfma_f32_32x32x16_bf16((a), (b), (c), 0, 0, 0)

__device__ __forceinline__ u16 f2bf(float f) {
    unsigned int u = __float_as_uint(f);
    u += 0x7fffu + ((u >> 16) & 1u);            // RNE
    return (u16)(u >> 16);
}
__device__ __forceinline__ float bf2f(u16 h) {
    return __uint_as_float(((unsigned int)h) << 16);
}
__device__ __forceinline__ unsigned int cvt_pk_bf16(float a, float b) {
    unsigned int r;
    asm("v_cvt_pk_bf16_f32 %0, %1, %2" : "=v"(r) : "v"(a), "v"(b));
    return r;
}
// async global->LDS, 16B/lane; LDS dest = wave-uniform base + lane*16
__device__ __forceinline__ void gl16(void* lds, const void* g) {
    __builtin_amdgcn_global_load_lds(
        (__attribute__((address_space(1))) void*)(g),
        (__attribute__((address_space(3))) void*)(lds), 16, 0, 0);
}

// ---------------------------------------------------------------------------
// x (fp32, 4096x1024) -> bf16
// ---------------------------------------------------------------------------
__global__ __launch_bounds__(256) void cvt_x(const float* __restrict__ X,
                                             u16* __restrict__ Y)
{
    const int i = blockIdx.x * 256 + threadIdx.x;
    const float4 a = *(const float4*)(X + (size_t)i * 8);
    const float4 b = *(const float4*)(X + (size_t)i * 8 + 4);
    s16x8 o;
    o[0] = (short)f2bf(a.x); o[1] = (short)f2bf(a.y);
    o[2] = (short)f2bf(a.z); o[3] = (short)f2bf(a.w);
    o[4] = (short)f2bf(b.x); o[5] = (short)f2bf(b.y);
    o[6] = (short)f2bf(b.z); o[7] = (short)f2bf(b.w);
    *(s16x8*)(Y + (size_t)i * 8) = o;
}

// ---------------------------------------------------------------------------
// W (fp32 [K][N]) -> Wt (bf16 [N][K]); z selects weight. 32x32 LDS transpose.
// ---------------------------------------------------------------------------
__global__ __launch_bounds__(256) void wtrans4(
    const float* __restrict__ W0, const float* __restrict__ W1,
    const float* __restrict__ W2, const float* __restrict__ W3,
    u16* __restrict__ T0, u16* __restrict__ T1,
    u16* __restrict__ T2, u16* __restrict__ T3)
{
    const float* W; u16* T;
    switch (blockIdx.z) {
        case 0: W = W0; T = T0; break;
        case 1: W = W1; T = T1; break;
        case 2: W = W2; T = T2; break;
        default: W = W3; T = T3; break;
    }
    __shared__ float tile[32][33];
    const int n0 = blockIdx.x * 32, k0 = blockIdx.y * 32;
    const int c = threadIdx.x & 31, rr = threadIdx.x >> 5;
#pragma unroll
    for (int i = 0; i < 4; ++i) {
        const int k = rr + i * 8;
        tile[k][c] = W[(size_t)(k0 + k) * DIM_ + n0 + c];
    }
    __syncthreads();
#pragma unroll
    for (int i = 0; i < 4; ++i) {
        const int n = rr + i * 8;
        T[(size_t)(n0 + n) * DIM_ + k0 + c] = f2bf(tile[c][n]);
    }
}

// ---------------------------------------------------------------------------
// concat biases: bias3[0:1024)=bq, [1024:2048)=bk, [2048:3072)=bv
// ---------------------------------------------------------------------------
__global__ __launch_bounds__(256) void cat_bias(
    const float* __restrict__ q, const float* __restrict__ k,
    const float* __restrict__ v, float* __restrict__ o)
{
    const int i = blockIdx.x * 256 + threadIdx.x;   // grid 12 -> 3072
    o[i] = (i < 1024) ? q[i] : ((i < 2048) ? k[i - 1024] : v[i - 2048]);
}

// ---------------------------------------------------------------------------
// bf16 MFMA GEMM, tile 128 x BN, BK=64, 256 threads (4 waves, 2x2 quadrants).
// A,Bt staged via global_load_lds (16B) into linear LDS, XOR-swizzled via
// pre-swizzled global source.
// EPI 0: bf16 head-major out into q|k|VT (VT = V transposed + s-bit2<->3 swap).
// EPI 1: fp32 row-major out.
// ---------------------------------------------------------------------------
template<int BN, int HMIN, int EPI>
__global__ __launch_bounds__(256, 3) void gemm_mfma(
    const u16* __restrict__ A, const u16* __restrict__ Bt,
    const float* __restrict__ bias, void* __restrict__ Yv)
{
    __shared__ u16 As[128 * 64];
    __shared__ u16 Bs[BN * 64];

    const int tid = threadIdx.x, lane = tid & 63, wid = tid >> 6;
    const int l15 = lane & 15, lg = lane >> 4;
    const int row0 = blockIdx.x * 128, col0 = blockIdx.y * BN;
    const int wr = (wid >> 1) * 64;
    const int wc = (wid & 1) * (BN / 2);
    constexpr int NM = 4, NN = BN / 32, BCH = BN / 32;

    const int l8 = lane >> 3, l7 = lane & 7;
    const int colE = ((l7 ^ l8) << 3);          // k-element offset (swizzled)

    const u16* aptr[4]; u16* aldp[4];
#pragma unroll
    for (int i = 0; i < 4; ++i) {
        const int ci = wid * 4 + i;
        const int rr = row0 + ci * 8 + l8;
        size_t a0;
        if (HMIN)
            a0 = (((size_t)(rr >> 11) * H_) * S_ + (rr & (S_ - 1))) * HD_ + colE;
        else
            a0 = (size_t)rr * DIM_ + colE;
        aptr[i] = A + a0;
        aldp[i] = As + ci * 512;
    }
    const u16* bptr[BCH]; u16* bldp[BCH];
#pragma unroll
    for (int i = 0; i < BCH; ++i) {
        const int ci = wid * BCH + i;
        const int rr = col0 + ci * 8 + l8;
        bptr[i] = Bt + (size_t)rr * DIM_ + colE;
        bldp[i] = Bs + ci * 512;
    }
    const size_t astep = HMIN ? (size_t)S_ * HD_ : 64;

    f32x4 acc[NM][NN];
#pragma unroll
    for (int m = 0; m < NM; ++m)
#pragma unroll
        for (int n = 0; n < NN; ++n) acc[m][n] = (f32x4){0.f, 0.f, 0.f, 0.f};

    for (int k0 = 0; k0 < DIM_; k0 += 64) {
        __syncthreads();   // previous frag reads done
#pragma unroll
        for (int i = 0; i < 4; ++i) gl16(aldp[i], aptr[i]);
#pragma unroll
        for (int i = 0; i < BCH; ++i) gl16(bldp[i], bptr[i]);
#pragma unroll
        for (int i = 0; i < 4; ++i) aptr[i] += astep;
#pragma unroll
        for (int i = 0; i < BCH; ++i) bptr[i] += 64;
        __syncthreads();   // loads drained

        s16x8 af[NM][2], bfr[NN][2];
#pragma unroll
        for (int m = 0; m < NM; ++m) {
            const int row = wr + m * 16 + l15;
#pragma unroll
            for (int kf = 0; kf < 2; ++kf)
                af[m][kf] = *(const s16x8*)&As[row * 64 +
                    (((kf * 64 + lg * 16) ^ ((l15 & 7) << 4)) >> 1)];
        }
#pragma unroll
        for (int n = 0; n < NN; ++n) {
            const int row = wc + n * 16 + l15;
#pragma unroll
            for (int kf = 0; kf < 2; ++kf)
                bfr[n][kf] = *(const s16x8*)&Bs[row * 64 +
                    (((kf * 64 + lg * 16) ^ ((l15 & 7) << 4)) >> 1)];
        }
        __builtin_amdgcn_s_setprio(1);
#pragma unroll
        for (int m = 0; m < NM; ++m)
#pragma unroll
            for (int n = 0; n < NN; ++n) {
                acc[m][n] = MFMA16(af[m][0], bfr[n][0], acc[m][n]);
                acc[m][n] = MFMA16(af[m][1], bfr[n][1], acc[m][n]);
            }
        __builtin_amdgcn_s_setprio(0);
    }

    // epilogue
#pragma unroll
    for (int n = 0; n < NN; ++n) {
        const int cc = col0 + wc + n * 16 + l15;
        const float bv = bias[cc];
#pragma unroll
        for (int m = 0; m < NM; ++m)
#pragma unroll
            for (int r = 0; r < 4; ++r) {
                const int rr = row0 + wr + m * 16 + lg * 4 + r;
                const float val = acc[m][n][r] + bv;
                if (EPI == 0) {
                    u16* Y = (u16*)Yv;
                    const int which = cc >> 10, hh = (cc >> 6) & (H_ - 1), d = cc & 63;
                    const int b = rr >> 11, s = rr & (S_ - 1);
                    size_t dst;
                    if (which == 2) {
                        // V^T, with s bits 2<->3 swapped (PV contraction perm)
                        const int sp = (s & ~12) | ((s & 4) << 1) | ((s & 8) >> 1);
                        dst = 2 * BHSD + ((size_t)(b * H_ + hh) * HD_ + d) * S_ + sp;
                    } else {
                        dst = (size_t)which * BHSD
                            + (((size_t)b * H_ + hh) * S_ + s) * HD_ + d;
                    }
                    Y[dst] = f2bf(val);
                } else {
                    ((float*)Yv)[(size_t)rr * DIM_ + cc] = val;
                }
            }
    }
}

// ---------------------------------------------------------------------------
// RoPE in place on bf16 [B*H][S][64]; z selects q (0) or k (1).
// ---------------------------------------------------------------------------
__global__ __launch_bounds__(256) void rope2(u16* __restrict__ Tq, u16* __restrict__ Tk,
                                             const float* __restrict__ theta)
{
    u16* T = blockIdx.z ? Tk : Tq;
    const int row = blockIdx.x * 8 + (threadIdx.x >> 5);
    const int j   = threadIdx.x & 31;
    const int s   = row & (S_ - 1);
    u16* rp = T + (size_t)row * HD_;
    const unsigned int pr = *(const unsigned int*)(rp + 2 * j);
    const float x1 = bf2f((u16)(pr & 0xffffu));
    const float x2 = bf2f((u16)(pr >> 16));
    float sn, cs;
    sincosf((float)s * theta[j], &sn, &cs);
    const u16 o1 = f2bf(x1 * cs - x2 * sn);
    const u16 o2 = f2bf(x1 * sn + x2 * cs);
    rp[j]      = o1;    // wave-internal: loads complete before stores
    rp[32 + j] = o2;
}

// ---------------------------------------------------------------------------
// bf16 MFMA causal flash attention, 32x32x16, swapped QK^T, KVBLK=64,
// double-buffered K/V staging, in-register softmax with defer-max.
// Grid (16 q-blocks zigzag, 32 bh). 256 threads = 4 waves; wave w owns
// q rows qb*128 + w*32 .. +31. Output in place into Q.
// ---------------------------------------------------------------------------
__global__ __launch_bounds__(256, 3) void attn_mfma(
    u16* __restrict__ Q, const u16* __restrict__ K, const u16* __restrict__ VT)
{
    const int x  = blockIdx.x;
    const int qb = (x & 1) ? (15 - (x >> 1)) : (x >> 1);
    const int bh = blockIdx.y;
    const int q0 = qb * 128;
    const int nt = 2 * qb + 2;

    u16* Qg = Q + (size_t)bh * S_ * HD_;
    const u16* Kg = K + (size_t)bh * S_ * HD_;
    const u16* Vg = VT + (size_t)bh * HD_ * S_;   // permuted [64][2048]

    __shared__ u16 KsA[2][64 * 64];   // 2 x 8 KB
    __shared__ u16 VsA[2][64 * 64];   // 2 x 8 KB

    const int tid = threadIdx.x, wid = tid >> 6, lane = tid & 63;
    const int l31 = lane & 31, h = lane >> 5;
    const int swz = l31 & 7;
    const int qw0 = q0 + wid * 32;

    // Q B-fragments: rows qw0 + l31, k = ks*16 + h*8
    s16x8 qf[4];
    {
        const u16* qrow = Qg + (size_t)(qw0 + l31) * HD_ + h * 8;
#pragma unroll
        for (int ks = 0; ks < 4; ++ks)
            qf[ks] = *(const s16x8*)(qrow + ks * 16);
    }

    f32x16 o0, o1;
#pragma unroll
    for (int r = 0; r < 16; ++r) { o0[r] = 0.f; o1[r] = 0.f; }
    float mI = -1e30f, lI = 0.f;

    // staging: per wave 2 K-chunk-groups + 2 V-chunk-groups
    const int srow = (lane >> 3);          // 0..7 within group
    const int sslt = (lane & 7);
#pragma unroll
    for (int i = 0; i < 2; ++i) {          // prologue: tile 0 -> buf 0
        const int grp = wid * 2 + i;
        const int row = grp * 8 + srow;
        const int ss  = (sslt ^ (row & 7)) << 3;
        gl16(&KsA[0][grp * 512], Kg + (size_t)row * HD_ + ss);
        gl16(&VsA[0][grp * 512], Vg + (size_t)row * S_ + ss);
    }
    __syncthreads();

    int buf = 0;
    for (int t = 0; t < nt; ++t) {
        const int j0 = t * 64;
        if (t + 1 < nt) {                  // prefetch next tile
            const int j1 = j0 + 64;
#pragma unroll
            for (int i = 0; i < 2; ++i) {
                const int grp = wid * 2 + i;
                const int row = grp * 8 + srow;
                const int ss  = (sslt ^ (row & 7)) << 3;
                gl16(&KsA[buf ^ 1][grp * 512], Kg + (size_t)(j1 + row) * HD_ + ss);
                gl16(&VsA[buf ^ 1][grp * 512], Vg + (size_t)row * S_ + j1 + ss);
            }
        }

        if (j0 <= qw0 + 31) {              // wave-uniform skip of masked tiles
            const u16* Kb = KsA[buf];
            const u16* Vb = VsA[buf];

            // ---- swapped QK^T: sc[sub][reg] = S[kv=j0+sub*32+crow(reg,h)][q=qw0+l31]
            f32x16 s0, s1;
#pragma unroll
            for (int r = 0; r < 16; ++r) { s0[r] = 0.f; s1[r] = 0.f; }
            __builtin_amdgcn_s_setprio(1);
#pragma unroll
            for (int ks = 0; ks < 4; ++ks) {
                const int sl = (((ks << 1) | h) ^ swz) << 3;
                const s16x8 k0 = *(const s16x8*)&Kb[l31 * 64 + sl];
                const s16x8 k1 = *(const s16x8*)&Kb[(32 + l31) * 64 + sl];
                s0 = MFMA32(k0, qf[ks], s0);
                s1 = MFMA32(k1, qf[ks], s1);
            }
            __builtin_amdgcn_s_setprio(0);

            if (j0 + 63 > qw0) {           // diagonal region: causal mask
                const int qg = qw0 + l31;
#pragma unroll
                for (int r = 0; r < 16; ++r) {
                    const int kvr = j0 + (r & 3) + ((r >> 2) << 3) + (h << 2);
                    if (kvr > qg)      s0[r] = -1e30f;
                    if (kvr + 32 > qg) s1[r] = -1e30f;
                }
            }

            // ---- online softmax with defer-max (THR = 64 score units)
            float pm = -1e30f;
#pragma unroll
            for (int r = 0; r < 16; ++r) pm = fmaxf(pm, fmaxf(s0[r], s1[r]));
            pm = fmaxf(pm, __shfl_xor(pm, 32));
            if (!__all(pm - mI <= 64.f)) {
                const float mn = fmaxf(mI, pm);
                const float al = exp2f((mI - mn) * CEXP);
                mI = mn; lI *= al;
#pragma unroll
                for (int r = 0; r < 16; ++r) {
                    const float at = __shfl(al, (r & 3) + ((r >> 2) << 3) + (h << 2));
                    o0[r] *= at; o1[r] *= at;
                }
            }
            const float mc = mI * CEXP;
            float p0[16], p1[16];
            float ps = 0.f;
#pragma unroll
            for (int r = 0; r < 16; ++r) { p0[r] = exp2f(s0[r] * CEXP - mc); ps += p0[r]; }
#pragma unroll
            for (int r = 0; r < 16; ++r) { p1[r] = exp2f(s1[r] * CEXP - mc); ps += p1[r]; }
            ps += __shfl_xor(ps, 32);
            lI += ps;

            // ---- PV: lane-local P fragments (contraction-permuted V^T)
            __builtin_amdgcn_s_setprio(1);
#pragma unroll
            for (int sub = 0; sub < 2; ++sub) {
#pragma unroll
                for (int j = 0; j < 2; ++j) {
                    union { s16x8 v; unsigned int w[4]; } pa;
#pragma unroll
                    for (int q2 = 0; q2 < 4; ++q2) {
                        const float a = sub ? p1[j * 8 + q2 * 2]     : p0[j * 8 + q2 * 2];
                        const float b = sub ? p1[j * 8 + q2 * 2 + 1] : p0[j * 8 + q2 * 2 + 1];
                        pa.w[q2] = cvt_pk_bf16(a, b);
                    }
                    const int sl = (((sub << 2) | (j << 1) | h) ^ swz) << 3;
                    const s16x8 v0 = *(const s16x8*)&Vb[l31 * 64 + sl];
                    const s16x8 v1 = *(const s16x8*)&Vb[(32 + l31) * 64 + sl];
                    o0 = MFMA32(pa.v, v0, o0);
                    o1 = MFMA32(pa.v, v1, o1);
                }
            }
            __builtin_amdgcn_s_setprio(0);
        }

        __syncthreads();                   // drains prefetch; buf handoff
        buf ^= 1;
    }

    // ---- epilogue: O / l, write bf16 in place into Q
    const float il = 1.f / lI;
#pragma unroll
    for (int r = 0; r < 16; ++r) {
        const int cr = (r & 3) + ((r >> 2) << 3) + (h << 2);
        const float ilr = __shfl(il, cr);
        u16* orow = Qg + (size_t)(qw0 + cr) * HD_;
        orow[l31]      = f2bf(o0[r] * ilr);
        orow[32 + l31] = f2bf(o1[r] * ilr);
    }
}

// ---------------------------------------------------------------------------
extern "C" void kernel_launch(void* const* d_in, const int* in_sizes, int n_in,
                              void* d_out, int out_size, void* d_ws, size_t ws_size,
                              hipStream_t stream)
{
    (void)in_sizes; (void)n_in; (void)out_size; (void)ws_size;
    const float* x     = (const float*)d_in[0];
    const float* theta = (const float*)d_in[2];
    const float* Wq    = (const float*)d_in[3];
    const float* bq    = (const float*)d_in[4];
    const float* Wk    = (const float*)d_in[5];
    const float* bk    = (const float*)d_in[6];
    const float* Wv    = (const float*)d_in[7];
    const float* bv    = (const float*)d_in[8];
    const float* Wo    = (const float*)d_in[9];
    const float* bo    = (const float*)d_in[10];
    float* out = (float*)d_out;

    // ws (u16): xb 4M | wtq|wtk|wtv 3M | wto 1M | q 4M | k 4M | VT 4M | bias3
    u16* xb  = (u16*)d_ws;
    u16* wtq = xb + (size_t)BS_ * DIM_;
    u16* wtk = wtq + (size_t)DIM_ * DIM_;
    u16* wtv = wtk + (size_t)DIM_ * DIM_;
    u16* wto = wtv + (size_t)DIM_ * DIM_;
    u16* qws = wto + (size_t)DIM_ * DIM_;
    u16* kws = qws + BHSD;
    u16* vtw = kws + BHSD;
    float* bias3 = (float*)(vtw + BHSD);

    const dim3 blk(256);

    cvt_x<<<dim3(BS_ * DIM_ / 8 / 256), blk, 0, stream>>>(x, xb);
    wtrans4<<<dim3(32, 32, 4), blk, 0, stream>>>(Wq, Wk, Wv, Wo, wtq, wtk, wtv, wto);
    cat_bias<<<dim3(12), blk, 0, stream>>>(bq, bk, bv, bias3);

    // fused QKV projection: q,k head-major; V written transposed+permuted
    gemm_mfma<128, 0, 0><<<dim3(32, 24), blk, 0, stream>>>(xb, wtq, bias3, qws);

    rope2<<<dim3(B_ * H_ * S_ / 8, 1, 2), blk, 0, stream>>>(qws, kws, theta);

    attn_mfma<<<dim3(16, 32), blk, 0, stream>>>(qws, kws, vtw);

    // output projection (head-major A in, fp32 row-major out)
    gemm_mfma<64, 1, 1><<<dim3(32, 16), blk, 0, stream>>>(qws, wto, bo, out);
}